// Round 1
// baseline (213.251 us; speedup 1.0000x reference)
//
#include <hip/hip_runtime.h>
#include <math.h>

#define N_ANCHOR   900
#define NUM_CAMS   6
#define CDIM       256
#define NUM_LEVELS 4
#define NUM_FIXED  7
#define NUM_LEARN  6
#define NUM_PTS    13
#define NUM_GROUPS 8
#define NW         2496   // NUM_CAMS*NUM_LEVELS*NUM_PTS*NUM_GROUPS
#define NI         312    // NUM_CAMS*NUM_LEVELS*NUM_PTS (softmax axis)
#define SUM_HW     14960
#define MAXJOBS    1248   // 6 cams * 4 corners * 52 (pt,level); divisible by 32
#define WSTRIDE    328    // w_rowT row stride: banks (i + 8g) % 32 -> conflict-free

#define FEAT_ELEMS (NUM_CAMS * SUM_HW * CDIM)   // 22,978,560
#define CONV_BLOCKS 5610                        // FEAT_ELEMS / 4096 exactly
#define PRE_BLOCKS  (N_ANCHOR + 156 + 16)       // 1072

typedef short short8 __attribute__((ext_vector_type(8)));
typedef float floatx4 __attribute__((ext_vector_type(4)));

__device__ __forceinline__ unsigned short f2bf(float x) {
  unsigned u = __float_as_uint(x);
  u += 0x7FFFu + ((u >> 16) & 1u);   // round-to-nearest-even
  return (unsigned short)(u >> 16);
}

__device__ __forceinline__ float bf2f(unsigned short u) {
  return __uint_as_float((unsigned)u << 16);
}

// ---------------------------------------------------------------------------
// Kernel 1: per-anchor prep (blocks 0..899) + wfc_w transpose/cvt (900..1055)
// + out_w transpose/cvt (1056..1071) + feature fp32->bf16 (1072..). block=256.
// ---------------------------------------------------------------------------
__global__ __launch_bounds__(256) void k_pre(
    const float* __restrict__ inst, const float* __restrict__ anchor,
    const float* __restrict__ l2i, const float* __restrict__ image_wh,
    const float* __restrict__ kp_fixed, const float* __restrict__ kp_w,
    const float* __restrict__ kp_b,
    const float* __restrict__ enc_w, const float* __restrict__ enc_b,
    const float* __restrict__ wfc_w, const float* __restrict__ out_w,
    const float* __restrict__ feature,
    unsigned short* __restrict__ qbf, unsigned short* __restrict__ wbf_t,
    unsigned short* __restrict__ owt, unsigned short* __restrict__ fbf,
    float* __restrict__ pts_out, float* __restrict__ valid_out) {
  const int t = threadIdx.x;

  if (blockIdx.x >= PRE_BLOCKS) {
    // ---- feature fp32 -> bf16 streaming convert ----
    const size_t base = (size_t)(blockIdx.x - PRE_BLOCKS) * 4096;
    #pragma unroll
    for (int i = 0; i < 4; ++i) {
      const size_t o = base + (size_t)i * 1024 + (size_t)t * 4;
      const float4 v = *(const float4*)&feature[o];
      ushort4 u;
      u.x = f2bf(v.x); u.y = f2bf(v.y); u.z = f2bf(v.z); u.w = f2bf(v.w);
      *(ushort4*)&fbf[o] = u;
    }
    return;
  }

  if (blockIdx.x >= N_ANCHOR) {
    // ---- transpose + bf16 convert: src[k][n] (stride ss) -> dst[n][k] ----
    const int bi = blockIdx.x - N_ANCHOR;
    const float* src; unsigned short* dst; int ss, n0, k0;
    if (bi < 156) { src = wfc_w; dst = wbf_t; ss = NW;   n0 = (bi % 39) * 64; k0 = (bi / 39) * 64; }
    else { const int b2 = bi - 156; src = out_w; dst = owt; ss = CDIM; n0 = (b2 % 4) * 64; k0 = (b2 / 4) * 64; }
    __shared__ float tile[64][65];
    #pragma unroll
    for (int i = 0; i < 4; ++i) {
      const int kr = (t >> 4) + i * 16;
      const int nc = (t & 15) * 4;
      const float4 v = *(const float4*)&src[(size_t)(k0 + kr) * ss + n0 + nc];
      tile[kr][nc + 0] = v.x; tile[kr][nc + 1] = v.y;
      tile[kr][nc + 2] = v.z; tile[kr][nc + 3] = v.w;
    }
    __syncthreads();
    #pragma unroll
    for (int i = 0; i < 4; ++i) {
      const int nr = (t >> 4) + i * 16;
      const int kc = (t & 15) * 4;
      ushort4 o;
      o.x = f2bf(tile[kc + 0][nr]);
      o.y = f2bf(tile[kc + 1][nr]);
      o.z = f2bf(tile[kc + 2][nr]);
      o.w = f2bf(tile[kc + 3][nr]);
      *(ushort4*)&dst[(size_t)(n0 + nr) * CDIM + k0 + kc] = o;
    }
    return;
  }

  // ---- per-anchor prep ----
  const int n = blockIdx.x;
  __shared__ float anc[11];
  __shared__ float learn[NUM_LEARN * 3];
  __shared__ float psum[8][NUM_LEARN * 3];
  __shared__ float kps[NUM_PTS][3];
  __shared__ float ins[CDIM];

  const float iv = inst[n * CDIM + t];
  ins[t] = iv;
  if (t < 11) anc[t] = anchor[n * 11 + t];
  __syncthreads();

  {
    float s = enc_b[t] + iv;
    #pragma unroll
    for (int k = 0; k < 11; ++k) s += anc[k] * enc_w[k * CDIM + t];
    qbf[n * CDIM + t] = f2bf(s);
  }

  if (t < 144) {
    const int c = t / 18, j = t % 18;
    float s = 0.0f;
    const int k0 = c * 32;
    #pragma unroll
    for (int k = 0; k < 32; ++k)
      s += ins[k0 + k] * kp_w[(k0 + k) * (NUM_LEARN * 3) + j];
    psum[c][j] = s;
  }
  __syncthreads();
  if (t < NUM_LEARN * 3) {
    float s = kp_b[t];
    #pragma unroll
    for (int c = 0; c < 8; ++c) s += psum[c][t];
    learn[t] = s;
  }
  __syncthreads();

  if (t < NUM_PTS) {
    const float sx = expf(anc[3]), sy = expf(anc[4]), sz = expf(anc[5]);
    float ox, oy, oz;
    if (t < NUM_FIXED) {
      ox = kp_fixed[t * 3 + 0]; oy = kp_fixed[t * 3 + 1]; oz = kp_fixed[t * 3 + 2];
    } else {
      const int j = (t - NUM_FIXED) * 3;
      ox = learn[j + 0]; oy = learn[j + 1]; oz = learn[j + 2];
    }
    ox *= sx; oy *= sy; oz *= sz;
    const float sn = anc[6], cs = anc[7];
    kps[t][0] = cs * ox - sn * oy + anc[0];
    kps[t][1] = sn * ox + cs * oy + anc[1];
    kps[t][2] = oz + anc[2];
  }
  __syncthreads();

  if (t < NUM_CAMS * NUM_PTS) {
    const int cam = t / NUM_PTS, p = t % NUM_PTS;
    const float* M = l2i + cam * 16;
    const float kx = kps[p][0], ky = kps[p][1], kz = kps[p][2];
    const float px = M[0] * kx + M[1] * ky + M[2]  * kz + M[3];
    const float py = M[4] * kx + M[5] * ky + M[6]  * kz + M[7];
    const float pz = M[8] * kx + M[9] * ky + M[10] * kz + M[11];
    const float d = fmaxf(pz, 1e-5f);
    const float u = (px / d) / image_wh[cam * 2 + 0];
    const float v = (py / d) / image_wh[cam * 2 + 1];
    const int o = n * NUM_CAMS * NUM_PTS + t;
    pts_out[o * 2 + 0] = u;
    pts_out[o * 2 + 1] = v;
    valid_out[o] = (pz > 1e-5f) ? 1.0f : 0.0f;
  }
}

// ---------------------------------------------------------------------------
// Kernel 2: MFMA GEMM  raw[900][2496] = q[900][256] @ wfc_w[256][2496] + b
// bf16 16x16x32. Block 256 (4 waves), tile M=64 x N=64. grid = (39, 15).
// ---------------------------------------------------------------------------
__global__ __launch_bounds__(256) void k_wgemm(
    const unsigned short* __restrict__ qbf,
    const unsigned short* __restrict__ wbf_t,
    const float* __restrict__ wfc_b, float* __restrict__ raw) {
  const int tid = threadIdx.x;
  const int w = tid >> 6;
  const int l = tid & 63;
  const int n0 = blockIdx.x * 64;
  const int m0 = blockIdx.y * 64;
  __shared__ unsigned short Bs[64 * 64];

  floatx4 acc[4];
  #pragma unroll
  for (int s = 0; s < 4; ++s) acc[s] = (floatx4){0.f, 0.f, 0.f, 0.f};

  const int arow = m0 + w * 16 + (l & 15);
  const bool arow_ok = arow < N_ANCHOR;
  const unsigned short* aptr = qbf + (size_t)arow * CDIM + (l >> 4) * 8;

  for (int k0 = 0; k0 < CDIM; k0 += 64) {
    #pragma unroll
    for (int i = 0; i < 2; ++i) {
      const int idx = tid + i * 256;
      const int n = idx >> 3, kg = idx & 7;
      const short8 bv =
          *(const short8*)&wbf_t[(size_t)(n0 + n) * CDIM + k0 + kg * 8];
      *(short8*)&Bs[n * 64 + ((kg ^ (n & 7)) * 8)] = bv;
    }
    __syncthreads();
    #pragma unroll
    for (int c = 0; c < 2; ++c) {
      short8 a = (short8){0, 0, 0, 0, 0, 0, 0, 0};
      if (arow_ok) a = *(const short8*)&aptr[k0 + c * 32];
      #pragma unroll
      for (int s = 0; s < 4; ++s) {
        const int nloc = s * 16 + (l & 15);
        const int k8 = c * 4 + (l >> 4);
        const short8 b = *(const short8*)&Bs[nloc * 64 + ((k8 ^ (nloc & 7)) * 8)];
        acc[s] = __builtin_amdgcn_mfma_f32_16x16x32_bf16(a, b, acc[s], 0, 0, 0);
      }
    }
    __syncthreads();
  }

  const int colb = n0 + (l & 15);
  const int rowb = m0 + w * 16 + (l >> 4) * 4;
  #pragma unroll
  for (int s = 0; s < 4; ++s) {
    const int col = colb + s * 16;
    const float bias = wfc_b[col];
    #pragma unroll
    for (int r = 0; r < 4; ++r) {
      const int row = rowb + r;
      if (row < N_ANCHOR)
        raw[(size_t)row * NW + col] = acc[s][r] + bias;
    }
  }
}

// ---------------------------------------------------------------------------
// Kernel 3 (mega): softmax + job list + gather (bf16) + reduce -> abf (bf16).
// grid = 900, block = 512 (8 waves). ~36 KB LDS -> 4 blocks/CU.
// ---------------------------------------------------------------------------
__global__ __launch_bounds__(512) void k_mega(
    const unsigned short* __restrict__ fbf,
    const int* __restrict__ spatial_shapes, const int* __restrict__ level_start,
    const float* __restrict__ pts, const float* __restrict__ valid,
    const float* __restrict__ raw,
    unsigned short* __restrict__ abf) {
  const int n = blockIdx.x;
  const int t = threadIdx.x;
  const int wv = t >> 6;         // wave 0..7
  const int lane = t & 63;       // channel chunk: channels 4*lane..+3
  const int g = lane >> 3;       // group of this chunk

  __shared__ float w_rowT[NUM_GROUPS * WSTRIDE];   // [g][i], stride 328
  __shared__ float uv_s[NUM_CAMS * NUM_PTS][2];
  __shared__ float val_s[NUM_CAMS * NUM_PTS];
  __shared__ float mx_s[NUM_GROUPS], inv_s[NUM_GROUPS];
  __shared__ int shp[NUM_LEVELS][2];
  __shared__ int lst[NUM_LEVELS];
  __shared__ int joff[MAXJOBS];
  __shared__ float jcf[MAXJOBS];
  __shared__ short jw_s[MAXJOBS];
  __shared__ int njobs;
  __shared__ float4 red4[8][64];

  // ---- phase 0: stage transposed logits + point data ----
  {
    const float4* src = (const float4*)(raw + (size_t)n * NW);
    for (int j4 = t; j4 < NW / 4; j4 += 512) {
      const float4 v = src[j4];
      const int i = j4 >> 1;           // point-level index
      const int gb = (j4 & 1) * 4;     // group base
      w_rowT[(gb + 0) * WSTRIDE + i] = v.x;
      w_rowT[(gb + 1) * WSTRIDE + i] = v.y;
      w_rowT[(gb + 2) * WSTRIDE + i] = v.z;
      w_rowT[(gb + 3) * WSTRIDE + i] = v.w;
    }
  }
  if (t < NUM_CAMS * NUM_PTS) {
    const int o = n * NUM_CAMS * NUM_PTS + t;
    uv_s[t][0] = pts[o * 2 + 0];
    uv_s[t][1] = pts[o * 2 + 1];
    val_s[t] = valid[o];
  }
  if (t < NUM_LEVELS) {
    shp[t][0] = spatial_shapes[t * 2 + 0];
    shp[t][1] = spatial_shapes[t * 2 + 1];
    lst[t] = level_start[t];
  }
  if (t == 0) njobs = 0;
  __syncthreads();

  // ---- phase 1a: softmax stats (wave wv owns group wv) ----
  {
    const float* wr = &w_rowT[wv * WSTRIDE];
    float m = -1e30f;
    for (int i = lane; i < NI; i += 64) m = fmaxf(m, wr[i]);
    #pragma unroll
    for (int o = 32; o > 0; o >>= 1) m = fmaxf(m, __shfl_down(m, o, 64));
    m = __shfl(m, 0, 64);
    float s = 0.0f;
    for (int i = lane; i < NI; i += 64) s += expf(wr[i] - m);
    #pragma unroll
    for (int o = 32; o > 0; o >>= 1) s += __shfl_down(s, o, 64);
    if (lane == 0) { mx_s[wv] = m; inv_s[wv] = 1.0f / s; }
  }

  // ---- phase 1b: job list via ballot compaction (1 atomic per wave/pass) --
  #pragma unroll
  for (int base = 0; base < MAXJOBS; base += 512) {
    const int jt = base + t;
    bool ok = false;
    int off = 0; short wbi = 0; float cf = 0.0f;
    if (jt < MAXJOBS) {
      const int cam = jt / 208;
      const int r = jt % 208;
      const int q = r / 52;
      const int pl = r % 52;
      const int p = pl >> 2, l = pl & 3;
      if (val_s[cam * NUM_PTS + p] != 0.0f) {
        const int H = shp[l][0], W = shp[l][1], st = lst[l];
        const float x = uv_s[cam * NUM_PTS + p][0] * (float)W - 0.5f;
        const float y = uv_s[cam * NUM_PTS + p][1] * (float)H - 0.5f;
        const float x0f = floorf(x), y0f = floorf(y);
        const float wx = x - x0f, wy = y - y0f;
        const int dx = q & 1, dy = q >> 1;
        const int xx = (int)x0f + dx;
        const int yy = (int)y0f + dy;
        if (xx >= 0 && xx < W && yy >= 0 && yy < H) {
          ok = true;
          off = (cam * SUM_HW + st + yy * W + xx) * CDIM;
          cf = (dx ? wx : 1.0f - wx) * (dy ? wy : 1.0f - wy);
          wbi = (short)(cam * 52 + l * NUM_PTS + p);
        }
      }
    }
    const unsigned long long mask = __ballot(ok);
    const int cnt = __popcll(mask);
    int wbase = 0;
    if (lane == 0 && cnt) wbase = atomicAdd(&njobs, cnt);
    wbase = __shfl(wbase, 0, 64);
    if (ok) {
      const int pos = wbase + __popcll(mask & ((1ull << lane) - 1ull));
      joff[pos] = off; jcf[pos] = cf; jw_s[pos] = wbi;
    }
  }
  __syncthreads();

  // ---- phase 2: pad job list; exp logits in place ----
  const int nj = njobs;
  const int padded = (nj + 31) & ~31;
  for (int j = nj + t; j < padded; j += 512) {
    joff[j] = 0; jcf[j] = 0.0f; jw_s[j] = 0;
  }
  for (int e = t; e < NUM_GROUPS * WSTRIDE; e += 512) {
    const int gg = e / WSTRIDE;
    w_rowT[e] = expf(w_rowT[e] - mx_s[gg]) * inv_s[gg];
  }
  __syncthreads();

  // ---- phase 3: gather (bf16 feature), 4 jobs in flight per wave ----
  float4 acc = make_float4(0.f, 0.f, 0.f, 0.f);
  const int cio = lane * 4;
  for (int j = wv; j < padded; j += 32) {
    ushort4 f[4]; float wg[4];
    #pragma unroll
    for (int i = 0; i < 4; ++i) {
      const int jj = j + i * 8;
      const int o = joff[jj];
      wg[i] = jcf[jj] * w_rowT[g * WSTRIDE + jw_s[jj]];
      f[i] = *(const ushort4*)&fbf[o + cio];
    }
    #pragma unroll
    for (int i = 0; i < 4; ++i) {
      acc.x += wg[i] * bf2f(f[i].x); acc.y += wg[i] * bf2f(f[i].y);
      acc.z += wg[i] * bf2f(f[i].z); acc.w += wg[i] * bf2f(f[i].w);
    }
  }
  red4[wv][lane] = acc;
  __syncthreads();

  // ---- phase 4: reduce 8 wave-partials -> abf[n][256] (bf16) ----
  if (t < 64) {
    float4 s = red4[0][t];
    #pragma unroll
    for (int w = 1; w < 8; ++w) {
      const float4 b = red4[w][t];
      s.x += b.x; s.y += b.y; s.z += b.z; s.w += b.w;
    }
    ushort4 o;
    o.x = f2bf(s.x); o.y = f2bf(s.y); o.z = f2bf(s.z); o.w = f2bf(s.w);
    *(ushort4*)&abf[(size_t)n * CDIM + t * 4] = o;
  }
}

// ---------------------------------------------------------------------------
// Kernel 4: MFMA GEMM out[900][256] = abf @ owt^T + out_b + inst.
// Same structure as k_wgemm; N=256. grid = (4, 15), block = 256.
// ---------------------------------------------------------------------------
__global__ __launch_bounds__(256) void k_ogemm(
    const unsigned short* __restrict__ abf,
    const unsigned short* __restrict__ owt,
    const float* __restrict__ out_b, const float* __restrict__ inst,
    float* __restrict__ out) {
  const int tid = threadIdx.x;
  const int w = tid >> 6;
  const int l = tid & 63;
  const int n0 = blockIdx.x * 64;
  const int m0 = blockIdx.y * 64;
  __shared__ unsigned short Bs[64 * 64];

  floatx4 acc[4];
  #pragma unroll
  for (int s = 0; s < 4; ++s) acc[s] = (floatx4){0.f, 0.f, 0.f, 0.f};

  const int arow = m0 + w * 16 + (l & 15);
  const bool arow_ok = arow < N_ANCHOR;
  const unsigned short* aptr = abf + (size_t)arow * CDIM + (l >> 4) * 8;

  for (int k0 = 0; k0 < CDIM; k0 += 64) {
    #pragma unroll
    for (int i = 0; i < 2; ++i) {
      const int idx = tid + i * 256;
      const int n = idx >> 3, kg = idx & 7;
      const short8 bv =
          *(const short8*)&owt[(size_t)(n0 + n) * CDIM + k0 + kg * 8];
      *(short8*)&Bs[n * 64 + ((kg ^ (n & 7)) * 8)] = bv;
    }
    __syncthreads();
    #pragma unroll
    for (int c = 0; c < 2; ++c) {
      short8 a = (short8){0, 0, 0, 0, 0, 0, 0, 0};
      if (arow_ok) a = *(const short8*)&aptr[k0 + c * 32];
      #pragma unroll
      for (int s = 0; s < 4; ++s) {
        const int nloc = s * 16 + (l & 15);
        const int k8 = c * 4 + (l >> 4);
        const short8 b = *(const short8*)&Bs[nloc * 64 + ((k8 ^ (nloc & 7)) * 8)];
        acc[s] = __builtin_amdgcn_mfma_f32_16x16x32_bf16(a, b, acc[s], 0, 0, 0);
      }
    }
    __syncthreads();
  }

  const int colb = n0 + (l & 15);
  const int rowb = m0 + w * 16 + (l >> 4) * 4;
  #pragma unroll
  for (int s = 0; s < 4; ++s) {
    const int col = colb + s * 16;
    const float bias = out_b[col];
    #pragma unroll
    for (int r = 0; r < 4; ++r) {
      const int row = rowb + r;
      if (row < N_ANCHOR)
        out[(size_t)row * CDIM + col] =
            acc[s][r] + bias + inst[(size_t)row * CDIM + col];
    }
  }
}

// ---------------------------------------------------------------------------
extern "C" void kernel_launch(void* const* d_in, const int* in_sizes, int n_in,
                              void* d_out, int out_size, void* d_ws, size_t ws_size,
                              hipStream_t stream) {
  const float* inst           = (const float*)d_in[0];
  const float* anchor         = (const float*)d_in[1];
  const float* feature        = (const float*)d_in[3];
  const int*   spatial_shapes = (const int*)d_in[4];
  const int*   level_start    = (const int*)d_in[5];
  const float* l2i            = (const float*)d_in[6];
  const float* image_wh       = (const float*)d_in[7];
  const float* enc_w          = (const float*)d_in[8];
  const float* enc_b          = (const float*)d_in[9];
  const float* kp_fixed       = (const float*)d_in[10];
  const float* kp_w           = (const float*)d_in[11];
  const float* kp_b           = (const float*)d_in[12];
  const float* wfc_w          = (const float*)d_in[13];
  const float* wfc_b          = (const float*)d_in[14];
  const float* out_w          = (const float*)d_in[15];
  const float* out_b          = (const float*)d_in[16];

  float* ws    = (float*)d_ws;
  float* pts   = ws;                                          // 900*78*2
  float* valid = pts + N_ANCHOR * NUM_CAMS * NUM_PTS * 2;     // 900*78
  float* wbuf  = valid + N_ANCHOR * NUM_CAMS * NUM_PTS;       // 900*2496
  unsigned short* qbf   = (unsigned short*)(wbuf + (size_t)N_ANCHOR * NW);
  unsigned short* wbf_t = qbf + N_ANCHOR * CDIM;              // 2496*256
  unsigned short* owt   = wbf_t + (size_t)NW * CDIM;          // 256*256
  unsigned short* abf   = owt + CDIM * CDIM;                  // 900*256
  unsigned short* fbf   = abf + N_ANCHOR * CDIM;              // 6*14960*256 bf16

  k_pre<<<PRE_BLOCKS + CONV_BLOCKS, 256, 0, stream>>>(
      inst, anchor, l2i, image_wh, kp_fixed, kp_w, kp_b, enc_w, enc_b,
      wfc_w, out_w, feature, qbf, wbf_t, owt, fbf, pts, valid);
  k_wgemm<<<dim3(NW / 64, (N_ANCHOR + 63) / 64), 256, 0, stream>>>(
      qbf, wbf_t, wfc_b, wbuf);
  k_mega<<<N_ANCHOR, 512, 0, stream>>>(
      fbf, spatial_shapes, level_start, pts, valid, wbuf, abf);
  k_ogemm<<<dim3(CDIM / 64, (N_ANCHOR + 63) / 64), 256, 0, stream>>>(
      abf, owt, out_b, inst, (float*)d_out);
}

// Round 2
// 196.800 us; speedup vs baseline: 1.0836x; 1.0836x over previous
//
#include <hip/hip_runtime.h>
#include <math.h>

#define N_ANCHOR   900
#define NUM_CAMS   6
#define CDIM       256
#define NUM_LEVELS 4
#define NUM_FIXED  7
#define NUM_LEARN  6
#define NUM_PTS    13
#define NUM_GROUPS 8
#define NW         2496   // NUM_CAMS*NUM_LEVELS*NUM_PTS*NUM_GROUPS
#define NI         312    // NUM_CAMS*NUM_LEVELS*NUM_PTS (softmax axis)
#define SUM_HW     14960
#define MAXJOBS    1248   // 6 cams * 4 corners * 52 (pt,level)
#define PADJOBS    1280   // MAXJOBS rounded up to multiple of 64
#define WSTRIDE    328    // w_rowT row stride: banks (i + 8g) % 32 -> conflict-free

typedef short short8 __attribute__((ext_vector_type(8)));
typedef float floatx4 __attribute__((ext_vector_type(4)));

__device__ __forceinline__ unsigned short f2bf(float x) {
  unsigned u = __float_as_uint(x);
  u += 0x7FFFu + ((u >> 16) & 1u);   // round-to-nearest-even
  return (unsigned short)(u >> 16);
}

// ---------------------------------------------------------------------------
// Kernel 1: per-anchor prep (blocks 0..899) + wfc_w transpose/cvt (900..1055)
// + out_w transpose/cvt (1056..1071). block = 256.
// ---------------------------------------------------------------------------
__global__ __launch_bounds__(256) void k_pre(
    const float* __restrict__ inst, const float* __restrict__ anchor,
    const float* __restrict__ l2i, const float* __restrict__ image_wh,
    const float* __restrict__ kp_fixed, const float* __restrict__ kp_w,
    const float* __restrict__ kp_b,
    const float* __restrict__ enc_w, const float* __restrict__ enc_b,
    const float* __restrict__ wfc_w, const float* __restrict__ out_w,
    unsigned short* __restrict__ qbf, unsigned short* __restrict__ wbf_t,
    unsigned short* __restrict__ owt,
    float* __restrict__ pts_out, float* __restrict__ valid_out) {
  const int t = threadIdx.x;

  if (blockIdx.x >= N_ANCHOR) {
    // ---- transpose + bf16 convert: src[k][n] (stride ss) -> dst[n][k] ----
    const int bi = blockIdx.x - N_ANCHOR;
    const float* src; unsigned short* dst; int ss, n0, k0;
    if (bi < 156) { src = wfc_w; dst = wbf_t; ss = NW;   n0 = (bi % 39) * 64; k0 = (bi / 39) * 64; }
    else { const int b2 = bi - 156; src = out_w; dst = owt; ss = CDIM; n0 = (b2 % 4) * 64; k0 = (b2 / 4) * 64; }
    __shared__ float tile[64][65];
    #pragma unroll
    for (int i = 0; i < 4; ++i) {
      const int kr = (t >> 4) + i * 16;
      const int nc = (t & 15) * 4;
      const float4 v = *(const float4*)&src[(size_t)(k0 + kr) * ss + n0 + nc];
      tile[kr][nc + 0] = v.x; tile[kr][nc + 1] = v.y;
      tile[kr][nc + 2] = v.z; tile[kr][nc + 3] = v.w;
    }
    __syncthreads();
    #pragma unroll
    for (int i = 0; i < 4; ++i) {
      const int nr = (t >> 4) + i * 16;
      const int kc = (t & 15) * 4;
      ushort4 o;
      o.x = f2bf(tile[kc + 0][nr]);
      o.y = f2bf(tile[kc + 1][nr]);
      o.z = f2bf(tile[kc + 2][nr]);
      o.w = f2bf(tile[kc + 3][nr]);
      *(ushort4*)&dst[(size_t)(n0 + nr) * CDIM + k0 + kc] = o;
    }
    return;
  }

  // ---- per-anchor prep ----
  const int n = blockIdx.x;
  __shared__ float anc[11];
  __shared__ float learn[NUM_LEARN * 3];
  __shared__ float psum[8][NUM_LEARN * 3];
  __shared__ float kps[NUM_PTS][3];
  __shared__ float ins[CDIM];

  const float iv = inst[n * CDIM + t];
  ins[t] = iv;
  if (t < 11) anc[t] = anchor[n * 11 + t];
  __syncthreads();

  {
    float s = enc_b[t] + iv;
    #pragma unroll
    for (int k = 0; k < 11; ++k) s += anc[k] * enc_w[k * CDIM + t];
    qbf[n * CDIM + t] = f2bf(s);
  }

  if (t < 144) {
    const int c = t / 18, j = t % 18;
    float s = 0.0f;
    const int k0 = c * 32;
    #pragma unroll
    for (int k = 0; k < 32; ++k)
      s += ins[k0 + k] * kp_w[(k0 + k) * (NUM_LEARN * 3) + j];
    psum[c][j] = s;
  }
  __syncthreads();
  if (t < NUM_LEARN * 3) {
    float s = kp_b[t];
    #pragma unroll
    for (int c = 0; c < 8; ++c) s += psum[c][t];
    learn[t] = s;
  }
  __syncthreads();

  if (t < NUM_PTS) {
    const float sx = expf(anc[3]), sy = expf(anc[4]), sz = expf(anc[5]);
    float ox, oy, oz;
    if (t < NUM_FIXED) {
      ox = kp_fixed[t * 3 + 0]; oy = kp_fixed[t * 3 + 1]; oz = kp_fixed[t * 3 + 2];
    } else {
      const int j = (t - NUM_FIXED) * 3;
      ox = learn[j + 0]; oy = learn[j + 1]; oz = learn[j + 2];
    }
    ox *= sx; oy *= sy; oz *= sz;
    const float sn = anc[6], cs = anc[7];
    kps[t][0] = cs * ox - sn * oy + anc[0];
    kps[t][1] = sn * ox + cs * oy + anc[1];
    kps[t][2] = oz + anc[2];
  }
  __syncthreads();

  if (t < NUM_CAMS * NUM_PTS) {
    const int cam = t / NUM_PTS, p = t % NUM_PTS;
    const float* M = l2i + cam * 16;
    const float kx = kps[p][0], ky = kps[p][1], kz = kps[p][2];
    const float px = M[0] * kx + M[1] * ky + M[2]  * kz + M[3];
    const float py = M[4] * kx + M[5] * ky + M[6]  * kz + M[7];
    const float pz = M[8] * kx + M[9] * ky + M[10] * kz + M[11];
    const float d = fmaxf(pz, 1e-5f);
    const float u = (px / d) / image_wh[cam * 2 + 0];
    const float v = (py / d) / image_wh[cam * 2 + 1];
    const int o = n * NUM_CAMS * NUM_PTS + t;
    pts_out[o * 2 + 0] = u;
    pts_out[o * 2 + 1] = v;
    valid_out[o] = (pz > 1e-5f) ? 1.0f : 0.0f;
  }
}

// ---------------------------------------------------------------------------
// Kernel 2: MFMA GEMM  raw[900][2496] = q[900][256] @ wfc_w[256][2496] + b
// bf16 16x16x32. Block 256 (4 waves), tile M=64 x N=64. grid = (39, 15).
// ---------------------------------------------------------------------------
__global__ __launch_bounds__(256) void k_wgemm(
    const unsigned short* __restrict__ qbf,
    const unsigned short* __restrict__ wbf_t,
    const float* __restrict__ wfc_b, float* __restrict__ raw) {
  const int tid = threadIdx.x;
  const int w = tid >> 6;
  const int l = tid & 63;
  const int n0 = blockIdx.x * 64;
  const int m0 = blockIdx.y * 64;
  __shared__ unsigned short Bs[64 * 64];

  floatx4 acc[4];
  #pragma unroll
  for (int s = 0; s < 4; ++s) acc[s] = (floatx4){0.f, 0.f, 0.f, 0.f};

  const int arow = m0 + w * 16 + (l & 15);
  const bool arow_ok = arow < N_ANCHOR;
  const unsigned short* aptr = qbf + (size_t)arow * CDIM + (l >> 4) * 8;

  for (int k0 = 0; k0 < CDIM; k0 += 64) {
    #pragma unroll
    for (int i = 0; i < 2; ++i) {
      const int idx = tid + i * 256;
      const int n = idx >> 3, kg = idx & 7;
      const short8 bv =
          *(const short8*)&wbf_t[(size_t)(n0 + n) * CDIM + k0 + kg * 8];
      *(short8*)&Bs[n * 64 + ((kg ^ (n & 7)) * 8)] = bv;
    }
    __syncthreads();
    #pragma unroll
    for (int c = 0; c < 2; ++c) {
      short8 a = (short8){0, 0, 0, 0, 0, 0, 0, 0};
      if (arow_ok) a = *(const short8*)&aptr[k0 + c * 32];
      #pragma unroll
      for (int s = 0; s < 4; ++s) {
        const int nloc = s * 16 + (l & 15);
        const int k8 = c * 4 + (l >> 4);
        const short8 b = *(const short8*)&Bs[nloc * 64 + ((k8 ^ (nloc & 7)) * 8)];
        acc[s] = __builtin_amdgcn_mfma_f32_16x16x32_bf16(a, b, acc[s], 0, 0, 0);
      }
    }
    __syncthreads();
  }

  const int colb = n0 + (l & 15);
  const int rowb = m0 + w * 16 + (l >> 4) * 4;
  #pragma unroll
  for (int s = 0; s < 4; ++s) {
    const int col = colb + s * 16;
    const float bias = wfc_b[col];
    #pragma unroll
    for (int r = 0; r < 4; ++r) {
      const int row = rowb + r;
      if (row < N_ANCHOR)
        raw[(size_t)row * NW + col] = acc[s][r] + bias;
    }
  }
}

// ---------------------------------------------------------------------------
// Kernel 3 (mega): softmax + job list + gather + reduce -> abf (bf16).
// grid = 900, block = 512 (8 waves). ~33 KB LDS -> 4 blocks/CU.
// Gather runs 8 jobs in flight per wave (latency-bound regime).
// ---------------------------------------------------------------------------
__global__ __launch_bounds__(512) void k_mega(
    const float* __restrict__ feature,
    const int* __restrict__ spatial_shapes, const int* __restrict__ level_start,
    const float* __restrict__ pts, const float* __restrict__ valid,
    const float* __restrict__ raw,
    unsigned short* __restrict__ abf) {
  const int n = blockIdx.x;
  const int t = threadIdx.x;
  const int wv = t >> 6;         // wave 0..7
  const int lane = t & 63;       // channel chunk: channels 4*lane..+3
  const int g = lane >> 3;       // group of this chunk

  __shared__ float w_rowT[NUM_GROUPS * WSTRIDE];   // [g][i], stride 328
  __shared__ float uv_s[NUM_CAMS * NUM_PTS][2];
  __shared__ float val_s[NUM_CAMS * NUM_PTS];
  __shared__ float mx_s[NUM_GROUPS], inv_s[NUM_GROUPS];
  __shared__ int shp[NUM_LEVELS][2];
  __shared__ int lst[NUM_LEVELS];
  __shared__ int joff[PADJOBS];
  __shared__ float jcf[PADJOBS];
  __shared__ short jw_s[PADJOBS];
  __shared__ int njobs;
  __shared__ float4 red4[8][64];

  // ---- phase 0: stage transposed logits + point data ----
  {
    const float4* src = (const float4*)(raw + (size_t)n * NW);
    for (int j4 = t; j4 < NW / 4; j4 += 512) {
      const float4 v = src[j4];
      const int i = j4 >> 1;           // point-level index
      const int gb = (j4 & 1) * 4;     // group base
      w_rowT[(gb + 0) * WSTRIDE + i] = v.x;
      w_rowT[(gb + 1) * WSTRIDE + i] = v.y;
      w_rowT[(gb + 2) * WSTRIDE + i] = v.z;
      w_rowT[(gb + 3) * WSTRIDE + i] = v.w;
    }
  }
  if (t < NUM_CAMS * NUM_PTS) {
    const int o = n * NUM_CAMS * NUM_PTS + t;
    uv_s[t][0] = pts[o * 2 + 0];
    uv_s[t][1] = pts[o * 2 + 1];
    val_s[t] = valid[o];
  }
  if (t < NUM_LEVELS) {
    shp[t][0] = spatial_shapes[t * 2 + 0];
    shp[t][1] = spatial_shapes[t * 2 + 1];
    lst[t] = level_start[t];
  }
  if (t == 0) njobs = 0;
  __syncthreads();

  // ---- phase 1a: softmax stats (wave wv owns group wv) ----
  {
    const float* wr = &w_rowT[wv * WSTRIDE];
    float m = -1e30f;
    for (int i = lane; i < NI; i += 64) m = fmaxf(m, wr[i]);
    #pragma unroll
    for (int o = 32; o > 0; o >>= 1) m = fmaxf(m, __shfl_down(m, o, 64));
    m = __shfl(m, 0, 64);
    float s = 0.0f;
    for (int i = lane; i < NI; i += 64) s += expf(wr[i] - m);
    #pragma unroll
    for (int o = 32; o > 0; o >>= 1) s += __shfl_down(s, o, 64);
    if (lane == 0) { mx_s[wv] = m; inv_s[wv] = 1.0f / s; }
  }

  // ---- phase 1b: job list via ballot compaction (1 atomic per wave/pass) --
  #pragma unroll
  for (int base = 0; base < MAXJOBS; base += 512) {
    const int jt = base + t;
    bool ok = false;
    int off = 0; short wbi = 0; float cf = 0.0f;
    if (jt < MAXJOBS) {
      const int cam = jt / 208;
      const int r = jt % 208;
      const int q = r / 52;
      const int pl = r % 52;
      const int p = pl >> 2, l = pl & 3;
      if (val_s[cam * NUM_PTS + p] != 0.0f) {
        const int H = shp[l][0], W = shp[l][1], st = lst[l];
        const float x = uv_s[cam * NUM_PTS + p][0] * (float)W - 0.5f;
        const float y = uv_s[cam * NUM_PTS + p][1] * (float)H - 0.5f;
        const float x0f = floorf(x), y0f = floorf(y);
        const float wx = x - x0f, wy = y - y0f;
        const int dx = q & 1, dy = q >> 1;
        const int xx = (int)x0f + dx;
        const int yy = (int)y0f + dy;
        if (xx >= 0 && xx < W && yy >= 0 && yy < H) {
          ok = true;
          off = (cam * SUM_HW + st + yy * W + xx) * CDIM;
          cf = (dx ? wx : 1.0f - wx) * (dy ? wy : 1.0f - wy);
          wbi = (short)(cam * 52 + l * NUM_PTS + p);
        }
      }
    }
    const unsigned long long mask = __ballot(ok);
    const int cnt = __popcll(mask);
    int wbase = 0;
    if (lane == 0 && cnt) wbase = atomicAdd(&njobs, cnt);
    wbase = __shfl(wbase, 0, 64);
    if (ok) {
      const int pos = wbase + __popcll(mask & ((1ull << lane) - 1ull));
      joff[pos] = off; jcf[pos] = cf; jw_s[pos] = wbi;
    }
  }
  __syncthreads();

  // ---- phase 2: pad job list (to x64); exp logits in place ----
  const int nj = njobs;
  const int padded = (nj + 63) & ~63;
  for (int j = nj + t; j < padded; j += 512) {
    joff[j] = 0; jcf[j] = 0.0f; jw_s[j] = 0;
  }
  for (int e = t; e < NUM_GROUPS * WSTRIDE; e += 512) {
    const int gg = e / WSTRIDE;
    w_rowT[e] = expf(w_rowT[e] - mx_s[gg]) * inv_s[gg];
  }
  __syncthreads();

  // ---- phase 3: gather, 8 jobs in flight per wave ----
  float4 acc = make_float4(0.f, 0.f, 0.f, 0.f);
  const int cio = lane * 4;
  const float* wgrp = &w_rowT[g * WSTRIDE];
  for (int j = wv; j < padded; j += 64) {
    float4 f[8]; float wg[8];
    #pragma unroll
    for (int i = 0; i < 8; ++i) {
      const int jj = j + i * 8;
      const int o = joff[jj];
      wg[i] = jcf[jj] * wgrp[jw_s[jj]];
      f[i] = *(const float4*)&feature[o + cio];
    }
    #pragma unroll
    for (int i = 0; i < 8; ++i) {
      acc.x += wg[i] * f[i].x; acc.y += wg[i] * f[i].y;
      acc.z += wg[i] * f[i].z; acc.w += wg[i] * f[i].w;
    }
  }
  red4[wv][lane] = acc;
  __syncthreads();

  // ---- phase 4: reduce 8 wave-partials -> abf[n][256] (bf16) ----
  if (t < 64) {
    float4 s = red4[0][t];
    #pragma unroll
    for (int w = 1; w < 8; ++w) {
      const float4 b = red4[w][t];
      s.x += b.x; s.y += b.y; s.z += b.z; s.w += b.w;
    }
    ushort4 o;
    o.x = f2bf(s.x); o.y = f2bf(s.y); o.z = f2bf(s.z); o.w = f2bf(s.w);
    *(ushort4*)&abf[(size_t)n * CDIM + t * 4] = o;
  }
}

// ---------------------------------------------------------------------------
// Kernel 4: MFMA GEMM out[900][256] = abf @ owt^T + out_b + inst.
// Same structure as k_wgemm; N=256. grid = (4, 15), block = 256.
// ---------------------------------------------------------------------------
__global__ __launch_bounds__(256) void k_ogemm(
    const unsigned short* __restrict__ abf,
    const unsigned short* __restrict__ owt,
    const float* __restrict__ out_b, const float* __restrict__ inst,
    float* __restrict__ out) {
  const int tid = threadIdx.x;
  const int w = tid >> 6;
  const int l = tid & 63;
  const int n0 = blockIdx.x * 64;
  const int m0 = blockIdx.y * 64;
  __shared__ unsigned short Bs[64 * 64];

  floatx4 acc[4];
  #pragma unroll
  for (int s = 0; s < 4; ++s) acc[s] = (floatx4){0.f, 0.f, 0.f, 0.f};

  const int arow = m0 + w * 16 + (l & 15);
  const bool arow_ok = arow < N_ANCHOR;
  const unsigned short* aptr = abf + (size_t)arow * CDIM + (l >> 4) * 8;

  for (int k0 = 0; k0 < CDIM; k0 += 64) {
    #pragma unroll
    for (int i = 0; i < 2; ++i) {
      const int idx = tid + i * 256;
      const int n = idx >> 3, kg = idx & 7;
      const short8 bv =
          *(const short8*)&owt[(size_t)(n0 + n) * CDIM + k0 + kg * 8];
      *(short8*)&Bs[n * 64 + ((kg ^ (n & 7)) * 8)] = bv;
    }
    __syncthreads();
    #pragma unroll
    for (int c = 0; c < 2; ++c) {
      short8 a = (short8){0, 0, 0, 0, 0, 0, 0, 0};
      if (arow_ok) a = *(const short8*)&aptr[k0 + c * 32];
      #pragma unroll
      for (int s = 0; s < 4; ++s) {
        const int nloc = s * 16 + (l & 15);
        const int k8 = c * 4 + (l >> 4);
        const short8 b = *(const short8*)&Bs[nloc * 64 + ((k8 ^ (nloc & 7)) * 8)];
        acc[s] = __builtin_amdgcn_mfma_f32_16x16x32_bf16(a, b, acc[s], 0, 0, 0);
      }
    }
    __syncthreads();
  }

  const int colb = n0 + (l & 15);
  const int rowb = m0 + w * 16 + (l >> 4) * 4;
  #pragma unroll
  for (int s = 0; s < 4; ++s) {
    const int col = colb + s * 16;
    const float bias = out_b[col];
    #pragma unroll
    for (int r = 0; r < 4; ++r) {
      const int row = rowb + r;
      if (row < N_ANCHOR)
        out[(size_t)row * CDIM + col] =
            acc[s][r] + bias + inst[(size_t)row * CDIM + col];
    }
  }
}

// ---------------------------------------------------------------------------
extern "C" void kernel_launch(void* const* d_in, const int* in_sizes, int n_in,
                              void* d_out, int out_size, void* d_ws, size_t ws_size,
                              hipStream_t stream) {
  const float* inst           = (const float*)d_in[0];
  const float* anchor         = (const float*)d_in[1];
  const float* feature        = (const float*)d_in[3];
  const int*   spatial_shapes = (const int*)d_in[4];
  const int*   level_start    = (const int*)d_in[5];
  const float* l2i            = (const float*)d_in[6];
  const float* image_wh       = (const float*)d_in[7];
  const float* enc_w          = (const float*)d_in[8];
  const float* enc_b          = (const float*)d_in[9];
  const float* kp_fixed       = (const float*)d_in[10];
  const float* kp_w           = (const float*)d_in[11];
  const float* kp_b           = (const float*)d_in[12];
  const float* wfc_w          = (const float*)d_in[13];
  const float* wfc_b          = (const float*)d_in[14];
  const float* out_w          = (const float*)d_in[15];
  const float* out_b          = (const float*)d_in[16];

  float* ws    = (float*)d_ws;
  float* pts   = ws;                                          // 900*78*2
  float* valid = pts + N_ANCHOR * NUM_CAMS * NUM_PTS * 2;     // 900*78
  float* wbuf  = valid + N_ANCHOR * NUM_CAMS * NUM_PTS;       // 900*2496
  unsigned short* qbf   = (unsigned short*)(wbuf + (size_t)N_ANCHOR * NW);
  unsigned short* wbf_t = qbf + N_ANCHOR * CDIM;              // 2496*256
  unsigned short* owt   = wbf_t + (size_t)NW * CDIM;          // 256*256
  unsigned short* abf   = owt + CDIM * CDIM;                  // 900*256

  k_pre<<<N_ANCHOR + 156 + 16, 256, 0, stream>>>(
      inst, anchor, l2i, image_wh, kp_fixed, kp_w, kp_b, enc_w, enc_b,
      wfc_w, out_w, qbf, wbf_t, owt, pts, valid);
  k_wgemm<<<dim3(NW / 64, (N_ANCHOR + 63) / 64), 256, 0, stream>>>(
      qbf, wbf_t, wfc_b, wbuf);
  k_mega<<<N_ANCHOR, 512, 0, stream>>>(
      feature, spatial_shapes, level_start, pts, valid, wbuf, abf);
  k_ogemm<<<dim3(CDIM / 64, (N_ANCHOR + 63) / 64), 256, 0, stream>>>(
      abf, owt, out_b, inst, (float*)d_out);
}